// Round 3
// baseline (37.891 us; speedup 1.0000x reference)
//
#include <hip/hip_runtime.h>

// YOLOv4 head transform, B=16, A=3, nc=80, H=W=76.
// x[b, a*85+ch, h, w] -> out[b, a*H*W + h*W + w, k], k in 0..83.
// R10: intra-block software pipelining. Each block owns 4 consecutive image
// rows of one (b,a) plane; one row (76 pos) per tile. Per tile: transform
// regs->LDS, barrier, ISSUE NEXT TILE'S LOADS, drain LDS->out, barrier.
// The prefetch hides load latency under the drain (R8/R9 showed the limiter
// is per-block latency bubbles, not occupancy or raw BW). Grid 48*19=912,
// no tails; h/w need no division. LDS 85*77*4=26.2KB, reg sets rA/rB double-
// buffer the staging (LDS single-buffered).

#define YHW 5776
#define W76 76
#define NROWS 4             // rows (tiles) per block
#define NRB 19              // row-groups per plane = 76/4
#define LSTRIDE 77
#define NTHREADS 512
#define QN 19               // float4s per channel row (76 floats)
#define NQ (85 * QN)        // 1615
#define NJ 4                // ceil(1615/512)

typedef float f4v __attribute__((ext_vector_type(4)));

__device__ __forceinline__ float fsigmoid(float v) {
    return __builtin_amdgcn_rcpf(1.0f + __expf(-v));
}

// toff is a compile-time constant at every call site (0/76/152/228 floats)
// -> folds into the global_load immediate offset; per-thread base addresses
// are CSE'd across tiles.
__device__ __forceinline__ void issue_loads(const float* __restrict__ src, int toff,
                                            f4v r[NJ], int tid) {
    #pragma unroll
    for (int j = 0; j < NJ; ++j) {
        const int idx = tid + NTHREADS * j;
        if (idx < NQ) {
            const int ch = idx / QN;
            const int q  = idx - ch * QN;
            r[j] = *reinterpret_cast<const f4v*>(src + (size_t)ch * YHW + 4 * q + toff);
        }
    }
}

__device__ __forceinline__ void transform(const f4v r[NJ], float (*lds)[LSTRIDE], int tid) {
    #pragma unroll
    for (int j = 0; j < NJ; ++j) {
        const int idx = tid + NTHREADS * j;
        if (idx < NQ) {
            const int ch = idx / QN;
            const int q  = idx - ch * QN;
            f4v v = r[j];
            int row;
            if (ch < 2) {                   // tx,ty -> sigmoid*1.2-0.1
                v.x = fsigmoid(v.x) * 1.2f - 0.1f;
                v.y = fsigmoid(v.y) * 1.2f - 0.1f;
                v.z = fsigmoid(v.z) * 1.2f - 0.1f;
                v.w = fsigmoid(v.w) * 1.2f - 0.1f;
                row = ch;
            } else if (ch < 4) {            // tw,th -> exp
                v.x = __expf(v.x); v.y = __expf(v.y);
                v.z = __expf(v.z); v.w = __expf(v.w);
                row = ch;
            } else {                        // det + classes -> sigmoid
                v.x = fsigmoid(v.x); v.y = fsigmoid(v.y);
                v.z = fsigmoid(v.z); v.w = fsigmoid(v.w);
                row = (ch == 4) ? 84 : ch - 1;   // class ch -> row k (4..83)
            }
            const int p4 = 4 * q;
            lds[row][p4 + 0] = v.x;
            lds[row][p4 + 1] = v.y;
            lds[row][p4 + 2] = v.z;
            lds[row][p4 + 3] = v.w;
        }
    }
}

__device__ __forceinline__ void drain(const float (*lds)[LSTRIDE], float* __restrict__ dst,
                                      int h, float ax, float ay, int tid) {
    const float inv = 1.0f / 76.0f;
    constexpr int total = W76 * 21;          // 1596
    #pragma unroll
    for (int u0 = 0; u0 < total; u0 += NTHREADS) {
        const int u = u0 + tid;
        if (u < total) {
            const int pp = u / 21;           // w coordinate directly
            const int c  = u - 21 * pp;
            f4v o;
            if (c == 0) {                    // box: rows 0..3, pure arithmetic
                const float sx = lds[0][pp];
                const float sy = lds[1][pp];
                const float ew = lds[2][pp];
                const float eh = lds[3][pp];
                const float bxc = (sx + (float)pp) * inv;
                const float byc = (sy + (float)h) * inv;
                const float bw  = ew * ax * inv;
                const float bh  = eh * ay * inv;
                const float bx1 = bxc - 0.5f * bw;
                const float by1 = byc - 0.5f * bh;
                o.x = bx1; o.y = by1; o.z = bx1 + bw; o.w = by1 + bh;
            } else {                         // classes k=4c..4c+3 at rows 4c..4c+3
                const float det = lds[84][pp];
                o.x = lds[4 * c + 0][pp] * det;
                o.y = lds[4 * c + 1][pp] * det;
                o.z = lds[4 * c + 2][pp] * det;
                o.w = lds[4 * c + 3][pp] * det;
            }
            *reinterpret_cast<f4v*>(dst + (size_t)pp * 84 + 4 * c) = o;
        }
    }
}

__global__ __launch_bounds__(NTHREADS) void yolo_kernel(const float* __restrict__ x,
                                                        float* __restrict__ out) {
    const int blk  = blockIdx.x;
    const int rb   = blk % NRB;
    const int ba   = blk / NRB;             // b*3 + a
    const int a    = ba % 3;
    const int row0 = rb * NROWS;

    __shared__ float lds[85][LSTRIDE];      // 26,180 B

    const int tid = threadIdx.x;
    const float* __restrict__ srcbase = x + (size_t)ba * 85 * YHW + (size_t)row0 * W76;
    float* __restrict__ dstbase = out + ((size_t)ba * YHW + (size_t)row0 * W76) * 84;

    const float ax = (a == 0) ? 1.5f : ((a == 1) ? 2.375f : 5.0f);
    const float ay = (a == 0) ? 2.0f : ((a == 1) ? 4.5f : 3.5f);

    f4v rA[NJ], rB[NJ];
    issue_loads(srcbase, 0, rA, tid);

#define STEP(T, CUR, NXT, ISLAST)                                              \
    transform(CUR, lds, tid);                                                  \
    __syncthreads();                                                           \
    if (!(ISLAST)) issue_loads(srcbase, ((T) + 1) * W76, NXT, tid);            \
    drain(lds, dstbase + (size_t)(T) * W76 * 84, row0 + (T), ax, ay, tid);     \
    if (!(ISLAST)) __syncthreads();

    STEP(0, rA, rB, 0)
    STEP(1, rB, rA, 0)
    STEP(2, rA, rB, 0)
    STEP(3, rB, rA, 1)
#undef STEP
}

extern "C" void kernel_launch(void* const* d_in, const int* in_sizes, int n_in,
                              void* d_out, int out_size, void* d_ws, size_t ws_size,
                              hipStream_t stream) {
    const float* x = (const float*)d_in[0];
    float* out = (float*)d_out;
    const int nblocks = 48 * NRB;           // 16*3*19 = 912
    yolo_kernel<<<nblocks, NTHREADS, 0, stream>>>(x, out);
}